// Round 4
// baseline (751.529 us; speedup 1.0000x reference)
//
#include <hip/hip_runtime.h>
#include <hip/hip_cooperative_groups.h>
namespace cg = cooperative_groups;

#define H 512
#define WID 1024
#define HW (H*WID)
#define B 4
#define K 8
#define NB 1024
#define G 128
#define NBLK1 128                          // fallback k1 blocks per image

// ws word (4-byte) layout
#define OFF_LOSS  0
#define OFF_TICK  1                        // completion ticket (u32)
#define OFF_FIN   16                       // B*K*8 floats: only [+4]=cnt used
#define OFF_SPART 512                      // B*K*G*8 floats (stride 8)
#define OFF_RED   (OFF_SPART + B*K*G*8)    // 2*B*K*NB u32
#define OFF_PART  (OFF_RED + 2*B*K*NB)     // B*G*K*NB packed u32 (pos<<16|cnt)

static __device__ __forceinline__ float frcp(float x){
#if __has_builtin(__builtin_amdgcn_rcpf)
  return __builtin_amdgcn_rcpf(x);
#else
  return 1.0f / x;
#endif
}
static __device__ __forceinline__ float fexp2(float x){
#if __has_builtin(__builtin_amdgcn_exp2f)
  return __builtin_amdgcn_exp2f(x);
#else
  return exp2f(x);
#endif
}
static __device__ __forceinline__ float ftanh(float x){
  return 1.0f - 2.0f * frcp(__expf(2.0f*x) + 1.0f);
}
static __device__ __forceinline__ float fsigmoid(float x){
  return frcp(1.0f + __expf(-x));
}

// ================= Cooperative mega-kernel: A:k1 B:k2 C:k3 D:k4a E:k4b =================
// 512 blocks x 1024 thr = exactly 2 blocks/CU (LDS ~50KB, VGPR capped 64).
// ti (inst staging) persists from phase A into phase C (saves 8MB re-read).
__global__ __launch_bounds__(1024, 8) void k_mega(const float* __restrict__ pred,
                                                  const int* __restrict__ inst,
                                                  float* __restrict__ ws,
                                                  unsigned int* __restrict__ part,
                                                  unsigned int* __restrict__ red,
                                                  float* __restrict__ out) {
  const int b = blockIdx.y, g = blockIdx.x;
  const int tid = threadIdx.x;
  const int wv = tid >> 6, lane = tid & 63;
  __shared__ int4         ti[1024];         // 16KB, persistent A->C
  __shared__ unsigned int hist[K*NB];       // 32KB; phase A aliases first 16KB as sigma
  __shared__ float  part5[16][5];
  __shared__ float4 finL[K];
  __shared__ float  vlocL[K];
  __shared__ float  wsum[16];
  __shared__ unsigned int redc[64], redp[64];
  __shared__ int    wtc[16], wtp[16];
  __shared__ double racc[16];
  cg::grid_group grid = cg::this_grid();
  const int base4 = g * 1024;               // 1024 int4-groups per block slice

  // ---------------- Phase A: per-(b,k) stats ----------------
  {
    float4* ts = (float4*)hist;             // alias (consumed before hist init)
    const float4* sig4 = (const float4*)(pred + (size_t)(8*b + 5) * HW);  // ch2 t=1
    const int4*   ins4 = (const int4*)(inst + (size_t)(2*b + 1) * HW);
    ti[tid] = ins4[base4 + tid];
    ts[tid] = sig4[base4 + tid];
    if (b == 0 && g == 0 && tid == 0) {
      atomicExch(ws + OFF_LOSS, 0.0f);
      atomicExch(((unsigned int*)ws) + OFF_TICK, 0u);
    }
    __syncthreads();
    const int kk = (wv & 7) + 1;            // wave w<8: quads [0,512); w>=8: [512,1024)
    const int qb = (wv < 8) ? 0 : 512;
    float cnt=0.f, sx=0.f, sy=0.f, ss=0.f, ss2=0.f;
    #pragma unroll
    for (int i = 0; i < 8; i++) {
      const int q = qb + lane + 64*i;
      const int4   iv = ti[q];
      const float4 sv = ts[q];
      const int p = (base4 + q) * 4;
      const float xm0 = (float)(p & (WID-1)) * (2.0f/2047.0f);
      const float ym  = (float)(p >> 10)     * (1.0f/1023.0f);
      const float m0 = (iv.x==kk)?1.f:0.f, m1=(iv.y==kk)?1.f:0.f,
                  m2 = (iv.z==kk)?1.f:0.f, m3=(iv.w==kk)?1.f:0.f;
      const float msum = (m0+m1)+(m2+m3);
      cnt += msum;
      sx  += msum*xm0 + (m1 + 2.0f*m2 + 3.0f*m3)*(2.0f/2047.0f);
      sy  += msum*ym;
      ss  += m0*sv.x + m1*sv.y + m2*sv.z + m3*sv.w;
      ss2 += m0*sv.x*sv.x + m1*sv.y*sv.y + m2*sv.z*sv.z + m3*sv.w*sv.w;
    }
    #pragma unroll
    for (int o=1;o<64;o<<=1){
      cnt+=__shfl_xor(cnt,o,64);
      sx +=__shfl_xor(sx, o,64);
      sy +=__shfl_xor(sy, o,64);
      ss +=__shfl_xor(ss, o,64);
      ss2+=__shfl_xor(ss2,o,64);
    }
    if (lane == 0) {
      part5[wv][0]=cnt; part5[wv][1]=sx; part5[wv][2]=sy; part5[wv][3]=ss; part5[wv][4]=ss2;
    }
    __syncthreads();
    if (tid < K*5) {
      const int k8 = tid / 5, c = tid % 5;
      ws[OFF_SPART + ((size_t)(b*K + k8)*G + g)*8 + c] = part5[k8][c] + part5[k8+8][c];
    }
  }
  __threadfence();
  grid.sync();

  // ---------------- Phase B: reduce spart -> finL, var loss ----------------
  {
    uint4 z = make_uint4(0u,0u,0u,0u);
    *(uint4*)&hist[tid*8]     = z;          // zero 8 u32/thread (8192 total)
    *(uint4*)&hist[tid*8 + 4] = z;
  }
  if (wv < K) {
    const float* p = ws + OFF_SPART + (size_t)(b*K + wv)*G*8;
    const float4 q0 = *(const float4*)(p + (size_t)lane*8);
    const float  e0 = p[(size_t)lane*8 + 4];
    const float4 q1 = *(const float4*)(p + (size_t)(lane+64)*8);
    const float  e1 = p[(size_t)(lane+64)*8 + 4];
    float a0=q0.x+q1.x, a1=q0.y+q1.y, a2=q0.z+q1.z, a3=q0.w+q1.w, a4=e0+e1;
    #pragma unroll
    for (int o=1;o<64;o<<=1){
      a0+=__shfl_xor(a0,o,64); a1+=__shfl_xor(a1,o,64); a2+=__shfl_xor(a2,o,64);
      a3+=__shfl_xor(a3,o,64); a4+=__shfl_xor(a4,o,64);
    }
    if (lane == 0) {
      const float cnt=a0, sx=a1, sy=a2, ss=a3, ss2=a4;
      const float present = (cnt > 0.0f) ? 1.0f : 0.0f;
      const float safe = fmaxf(cnt, 1.0f);
      const float cx = sx/safe, cy = sy/safe, sm = ss/safe;
      const float var = (ss2 - 2.0f*sm*ss + sm*sm*cnt)/safe;   // N_SIGMA=1
      const float sexp = expf(10.0f * sm);
      const float L2E = 1.4426950408889634f;
      finL[wv] = make_float4(-sexp*L2E,
                              2.0f*sexp*cx*L2E,
                              2.0f*sexp*cy*L2E,
                             -sexp*(cx*cx + cy*cy)*L2E + 10.0f);
      vlocL[wv] = present * 10.0f * var * (1.0f/3.0f);          // W_VAR=10, /(B-1)
      if (g == 0) ws[OFF_FIN + (b*K + wv)*8 + 4] = cnt;         // for phase E
    }
  }
  __syncthreads();

  // ---------------- Phase C: main pass ----------------
  {
    float4 fr[K];
    #pragma unroll
    for (int k=0;k<K;k++) fr[k] = finL[k];
    const float4* p0 = (const float4*)(pred + (size_t)(8*b+1)*HW);
    const float4* p1 = (const float4*)(pred + (size_t)(8*b+3)*HW);
    const float4* p3 = (const float4*)(pred + (size_t)(8*b+7)*HW);
    float sAcc = 0.0f;
    const int idx = base4 + tid;
    const int4   iv = ti[tid];              // from LDS, staged in phase A
    const float4 f0 = p0[idx];
    const float4 f1 = p1[idx];
    const float4 f3 = p3[idx];
    const int p = idx * 4;
    const float xm0 = (float)(p & (WID-1)) * (2.0f/2047.0f);
    const float ym  = (float)(p >> 10)     * (1.0f/1023.0f);
    const int ivv[4] = {iv.x, iv.y, iv.z, iv.w};
    float pxv[4], pyv[4], t2v[4], down[4];
    {
      const float a0v[4] = {f0.x, f0.y, f0.z, f0.w};
      const float a1v[4] = {f1.x, f1.y, f1.z, f1.w};
      #pragma unroll
      for (int e=0;e<4;e++){
        pxv[e] = ftanh(a0v[e]) + xm0 + (float)e*(2.0f/2047.0f);
        pyv[e] = ftanh(a1v[e]) + ym;
        t2v[e] = pxv[e]*pxv[e] + pyv[e]*pyv[e];
        down[e] = 0.0f;
      }
    }
    #pragma unroll
    for (int j=0;j<K;j++){
      const float4 f = fr[j];
      int buv[4]; unsigned addv[4];
      #pragma unroll
      for (int e=0;e<4;e++){
        const float u = fmaf(f.x, t2v[e], fmaf(f.y, pxv[e], fmaf(f.z, pyv[e], f.w)));
        const float v = fexp2(u);                 // 1024*dist in [0,1024]
        int vi = (int)v; vi = (vi > NB-1) ? NB-1 : vi;
        const bool own = (ivv[e] == j+1);
        if (own) down[e] = v;
        buv[e] = own ? (NB-1 - vi) : vi;
        addv[e] = own ? 0x10001u : 1u;
      }
      int cur = buv[0]; unsigned acc = addv[0];   // merge equal-bucket runs
      #pragma unroll
      for (int e=1;e<4;e++){
        const bool same = (buv[e] == cur);
        if (!same) atomicAdd(&hist[j*NB + cur], acc);
        acc = same ? acc + addv[e] : addv[e];
        cur = buv[e];
      }
      atomicAdd(&hist[j*NB + cur], acc);
    }
    {
      const float sdv[4] = {fsigmoid(f3.x), fsigmoid(f3.y), fsigmoid(f3.z), fsigmoid(f3.w)};
      #pragma unroll
      for (int e=0;e<4;e++){
        const float d  = (ivv[e] == 0) ? 0.0f : down[e] * (1.0f/1024.0f);
        const float df = sdv[e] - d;
        sAcc += df*df;
      }
    }
    __syncthreads();
    unsigned int* dst = part + ((size_t)b*G + g)*(K*NB);
    *(uint4*)&dst[tid*8]     = *(const uint4*)&hist[tid*8];
    *(uint4*)&dst[tid*8 + 4] = *(const uint4*)&hist[tid*8 + 4];
    #pragma unroll
    for (int o=1;o<64;o<<=1) sAcc += __shfl_xor(sAcc, o, 64);
    if (lane == 0) wsum[wv] = sAcc;
    __syncthreads();
    if (tid == 0) {
      float tot = 0.f;
      #pragma unroll
      for (int w = 0; w < 16; w++) tot += wsum[w];
      float add = tot * (1.0f/((float)HW * 3.0f));   // W_SEED /npix /(B-1)
      if (g == 0) {
        #pragma unroll
        for (int k = 0; k < K; k++) add += vlocL[k]; // var loss, once per image
      }
      atomicAdd(ws + OFF_LOSS, add);
    }
  }
  __threadfence();
  grid.sync();

  // ---------------- Phase D: G-way histogram reduction (all 512 blocks) ----------------
  const int id = b*G + g;                   // 0..511
  {
    const int bk = id >> 4, chunk = id & 15;
    const int b_ = bk >> 3, k_ = bk & 7;
    if (tid < 64)            redc[tid]      = 0u;
    else if (tid < 128)      redp[tid - 64] = 0u;
    __syncthreads();
    const int bu = chunk*64 + lane;
    unsigned rc = 0, rp = 0;
    #pragma unroll
    for (int i = 0; i < 8; i++) {
      const int gg = wv + 16*i;
      const unsigned v = part[((size_t)(b_*G + gg)*K + k_)*NB + bu];
      rc += v & 0xFFFFu;
      rp += v >> 16;
    }
    atomicAdd(&redc[lane], rc);
    atomicAdd(&redp[lane], rp);
    __syncthreads();
    if (tid < 64) {
      const int bu2 = chunk*64 + tid;
      red[(size_t)bk*NB + bu2]          = redc[tid];
      red[(size_t)B*K*NB + bk*NB + bu2] = redp[tid];
    }
  }
  __threadfence();
  grid.sync();

  // ---------------- Phase E: Lovász (32 blocks), ticket writes output ----------------
  if (id < B*K) {
    const int bk = id;
    const float cntF = ws[OFF_FIN + bk*8 + 4];
    if (cntF > 0.0f) {
      const double Pd = (double)cntF;
      const int bu = NB-1 - tid;                 // descending error order
      const unsigned c0 = red[(size_t)bk*NB + bu];
      const unsigned q0 = red[(size_t)B*K*NB + bk*NB + bu];
      int ic = (int)c0, ip = (int)q0;
      #pragma unroll
      for (int o=1;o<64;o<<=1){
        const int vc = __shfl_up(ic, o, 64);
        const int vp = __shfl_up(ip, o, 64);
        if (lane >= o) { ic += vc; ip += vp; }
      }
      if (lane == 63) { wtc[wv] = ic; wtp[wv] = ip; }
      __syncthreads();
      int offc = 0, offp = 0;
      for (int w = 0; w < wv; w++) { offc += wtc[w]; offp += wtp[w]; }
      int irun = offc + ic - (int)c0;            // exclusive prefixes
      int crun = offp + ip - (int)q0;
      double acc = 0.0;
      if (c0) {
        const double jac0 = (irun==0) ? 0.0 : 1.0 - (Pd - crun)/(Pd + irun - crun);
        const int ir1 = irun + (int)c0, cr1 = crun + (int)q0;
        const double jac1 = 1.0 - (Pd - cr1)/(Pd + ir1 - cr1);
        acc = ((bu + 0.5) * (2.0/NB)) * (jac1 - jac0);
      }
      #pragma unroll
      for (int o=1;o<64;o<<=1) acc += __shfl_xor(acc, o, 64);
      if (lane == 0) racc[wv] = acc;
      __syncthreads();
      if (tid == 0) {
        double tot = 0.0;
        #pragma unroll
        for (int w = 0; w < 16; w++) tot += racc[w];
        atomicAdd(ws + OFF_LOSS, (float)(tot * (1.0/3.0)));   // W_INST=1, /(B-1)
      }
    }
    if (tid == 0) {
      __threadfence();
      unsigned int* wsu = (unsigned int*)ws;
      const unsigned int old = atomicAdd(&wsu[OFF_TICK], 1u);
      if (old == (unsigned)(B*K - 1)) {
        __threadfence();
        out[0] = *((volatile float*)(ws + OFF_LOSS));
      }
    }
  }
}

// ======================= Fallback path (round-3 kernels, unchanged) =======================
__global__ __launch_bounds__(512) void k1_stats(const float* __restrict__ pred,
                                                const int* __restrict__ inst,
                                                float* __restrict__ ws) {
  const int b = blockIdx.y;
  __shared__ int4   ti[1024];
  __shared__ float4 ts[1024];
  __shared__ float  part5[K][5];
  const float4* sig4 = (const float4*)(pred + (size_t)(8*b + 5) * HW);
  const int4*   ins4 = (const int4*)(inst + (size_t)(2*b + 1) * HW);
  const int base4 = blockIdx.x * 1024;
  #pragma unroll
  for (int i = 0; i < 2; i++) {
    const int q = threadIdx.x + i*512;
    ti[q] = ins4[base4 + q];
    ts[q] = sig4[base4 + q];
  }
  __syncthreads();
  const int wv = threadIdx.x >> 6, lane = threadIdx.x & 63;
  const int kk = wv + 1;
  float cnt=0.f, sx=0.f, sy=0.f, ss=0.f, ss2=0.f;
  #pragma unroll
  for (int j = 0; j < 16; j++) {
    const int q = lane + 64*j;
    const int4   iv = ti[q];
    const float4 sv = ts[q];
    const int p = (base4 + q) * 4;
    const float xm0 = (float)(p & (WID-1)) * (2.0f/2047.0f);
    const float ym  = (float)(p >> 10)     * (1.0f/1023.0f);
    const float m0 = (iv.x==kk)?1.f:0.f, m1=(iv.y==kk)?1.f:0.f,
                m2 = (iv.z==kk)?1.f:0.f, m3=(iv.w==kk)?1.f:0.f;
    const float msum = (m0+m1)+(m2+m3);
    cnt += msum;
    sx  += msum*xm0 + (m1 + 2.0f*m2 + 3.0f*m3)*(2.0f/2047.0f);
    sy  += msum*ym;
    ss  += m0*sv.x + m1*sv.y + m2*sv.z + m3*sv.w;
    ss2 += m0*sv.x*sv.x + m1*sv.y*sv.y + m2*sv.z*sv.z + m3*sv.w*sv.w;
  }
  #pragma unroll
  for (int o=1;o<64;o<<=1){
    cnt+=__shfl_xor(cnt,o,64);
    sx +=__shfl_xor(sx, o,64);
    sy +=__shfl_xor(sy, o,64);
    ss +=__shfl_xor(ss, o,64);
    ss2+=__shfl_xor(ss2,o,64);
  }
  if (lane == 0) {
    part5[wv][0]=cnt; part5[wv][1]=sx; part5[wv][2]=sy; part5[wv][3]=ss; part5[wv][4]=ss2;
  }
  __syncthreads();
  if (threadIdx.x < K*8) {
    const int w = threadIdx.x >> 3, c = threadIdx.x & 7;
    if (c < 5)
      ws[OFF_SPART + ((size_t)(b*K + w)*NBLK1 + blockIdx.x)*8 + c] = part5[w][c];
  }
}

__global__ __launch_bounds__(1024, 8) void k3_fb(const float* __restrict__ pred,
                                                 const int* __restrict__ inst,
                                                 float* __restrict__ ws,
                                                 unsigned int* __restrict__ part) {
  const int b = blockIdx.y, g = blockIdx.x;
  __shared__ unsigned int hist[K*NB];
  __shared__ float4 finL[K];
  __shared__ float  vlocL[K];
  for (int i = threadIdx.x*4; i < K*NB; i += 1024*4)
    *(uint4*)&hist[i] = make_uint4(0u,0u,0u,0u);
  const int wv = threadIdx.x >> 6, lane = threadIdx.x & 63;
  if (wv < K) {
    const float* p = ws + OFF_SPART + (size_t)(b*K + wv)*NBLK1*8;
    const float4 q0 = *(const float4*)(p + (size_t)lane*8);
    const float  e0 = p[(size_t)lane*8 + 4];
    const float4 q1 = *(const float4*)(p + (size_t)(lane+64)*8);
    const float  e1 = p[(size_t)(lane+64)*8 + 4];
    float a0=q0.x+q1.x, a1=q0.y+q1.y, a2=q0.z+q1.z, a3=q0.w+q1.w, a4=e0+e1;
    #pragma unroll
    for (int o=1;o<64;o<<=1){
      a0+=__shfl_xor(a0,o,64); a1+=__shfl_xor(a1,o,64); a2+=__shfl_xor(a2,o,64);
      a3+=__shfl_xor(a3,o,64); a4+=__shfl_xor(a4,o,64);
    }
    if (lane == 0) {
      const float cnt=a0, sx=a1, sy=a2, ss=a3, ss2=a4;
      const float present = (cnt > 0.0f) ? 1.0f : 0.0f;
      const float safe = fmaxf(cnt, 1.0f);
      const float cx = sx/safe, cy = sy/safe, sm = ss/safe;
      const float var = (ss2 - 2.0f*sm*ss + sm*sm*cnt)/safe;
      const float sexp = expf(10.0f * sm);
      const float L2E = 1.4426950408889634f;
      finL[wv] = make_float4(-sexp*L2E, 2.0f*sexp*cx*L2E, 2.0f*sexp*cy*L2E,
                             -sexp*(cx*cx + cy*cy)*L2E + 10.0f);
      vlocL[wv] = present * 10.0f * var * (1.0f/3.0f);
      if (g == 0) ws[OFF_FIN + (b*K + wv)*8 + 4] = cnt;
    }
  }
  __syncthreads();
  float4 fr[K];
  #pragma unroll
  for (int k=0;k<K;k++) fr[k] = finL[k];
  const float4* p0 = (const float4*)(pred + (size_t)(8*b+1)*HW);
  const float4* p1 = (const float4*)(pred + (size_t)(8*b+3)*HW);
  const float4* p3 = (const float4*)(pred + (size_t)(8*b+7)*HW);
  const int4*   in4 = (const int4*)(inst + (size_t)(2*b+1)*HW);
  float sAcc = 0.0f;
  const int idx = g*1024 + threadIdx.x;
  {
    const int4   iv = in4[idx];
    const float4 f0 = p0[idx];
    const float4 f1 = p1[idx];
    const float4 f3 = p3[idx];
    const int p = idx * 4;
    const float xm0 = (float)(p & (WID-1)) * (2.0f/2047.0f);
    const float ym  = (float)(p >> 10)     * (1.0f/1023.0f);
    const int ivv[4] = {iv.x, iv.y, iv.z, iv.w};
    float pxv[4], pyv[4], t2v[4], down[4];
    {
      const float a0v[4] = {f0.x, f0.y, f0.z, f0.w};
      const float a1v[4] = {f1.x, f1.y, f1.z, f1.w};
      #pragma unroll
      for (int e=0;e<4;e++){
        pxv[e] = ftanh(a0v[e]) + xm0 + (float)e*(2.0f/2047.0f);
        pyv[e] = ftanh(a1v[e]) + ym;
        t2v[e] = pxv[e]*pxv[e] + pyv[e]*pyv[e];
        down[e] = 0.0f;
      }
    }
    #pragma unroll
    for (int j=0;j<K;j++){
      const float4 f = fr[j];
      int buv[4]; unsigned addv[4];
      #pragma unroll
      for (int e=0;e<4;e++){
        const float u = fmaf(f.x, t2v[e], fmaf(f.y, pxv[e], fmaf(f.z, pyv[e], f.w)));
        const float v = fexp2(u);
        int vi = (int)v; vi = (vi > NB-1) ? NB-1 : vi;
        const bool own = (ivv[e] == j+1);
        if (own) down[e] = v;
        buv[e] = own ? (NB-1 - vi) : vi;
        addv[e] = own ? 0x10001u : 1u;
      }
      int cur = buv[0]; unsigned acc = addv[0];
      #pragma unroll
      for (int e=1;e<4;e++){
        const bool same = (buv[e] == cur);
        if (!same) atomicAdd(&hist[j*NB + cur], acc);
        acc = same ? acc + addv[e] : addv[e];
        cur = buv[e];
      }
      atomicAdd(&hist[j*NB + cur], acc);
    }
    {
      const float sdv[4] = {fsigmoid(f3.x), fsigmoid(f3.y), fsigmoid(f3.z), fsigmoid(f3.w)};
      #pragma unroll
      for (int e=0;e<4;e++){
        const float d  = (ivv[e] == 0) ? 0.0f : down[e] * (1.0f/1024.0f);
        const float df = sdv[e] - d;
        sAcc += df*df;
      }
    }
  }
  __syncthreads();
  unsigned int* dst = part + ((size_t)b*G + g)*(K*NB);
  for (int i = threadIdx.x*4; i < K*NB; i += 1024*4)
    *(uint4*)&dst[i] = *(const uint4*)&hist[i];
  #pragma unroll
  for (int o=1;o<64;o<<=1) sAcc += __shfl_xor(sAcc, o, 64);
  __shared__ float wsum[16];
  if (lane == 0) wsum[wv] = sAcc;
  __syncthreads();
  if (threadIdx.x == 0) {
    float tot = 0.f;
    #pragma unroll
    for (int w = 0; w < 16; w++) tot += wsum[w];
    float add = tot * (1.0f/((float)HW * 3.0f));
    if (g == 0) {
      #pragma unroll
      for (int k = 0; k < K; k++) add += vlocL[k];
    }
    atomicAdd(ws + OFF_LOSS, add);
  }
}

__global__ __launch_bounds__(128) void k4a_reduce(const unsigned int* __restrict__ part,
                                                  unsigned int* __restrict__ red) {
  const int bk = blockIdx.x, c = blockIdx.y;
  const int b = bk >> 3, k = bk & 7;
  const int bu = c*128 + threadIdx.x;
  const unsigned int* base = part + (size_t)b*G*K*NB + (size_t)k*NB + bu;
  unsigned int rc = 0, rp = 0;
  #pragma unroll 8
  for (int g = 0; g < G; g++) {
    const unsigned int v = base[(size_t)g*K*NB];
    rc += v & 0xFFFFu;
    rp += v >> 16;
  }
  red[bk*NB + bu]            = rc;
  red[B*K*NB + bk*NB + bu]   = rp;
}

__global__ __launch_bounds__(256) void k4b_lovasz(const unsigned int* __restrict__ red,
                                                   float* __restrict__ ws,
                                                   float* __restrict__ out) {
  const int bk = blockIdx.x;
  const float cntF = ws[OFF_FIN + bk*8 + 4];
  const int t = threadIdx.x;
  if (cntF > 0.0f) {
    const double Pd = (double)cntF;
    const int lane = t & 63, wv = t >> 6;
    unsigned int cnt[4], pos[4];
    #pragma unroll
    for (int j = 0; j < 4; j++) {
      const int bu = NB-1 - (t*4 + j);
      cnt[j] = red[bk*NB + bu];
      pos[j] = red[B*K*NB + bk*NB + bu];
    }
    const int lc = (int)(cnt[0]+cnt[1]+cnt[2]+cnt[3]);
    const int lp = (int)(pos[0]+pos[1]+pos[2]+pos[3]);
    int ic = lc, ip = lp;
    #pragma unroll
    for (int o=1;o<64;o<<=1){
      const int vc = __shfl_up(ic, o, 64);
      const int vp = __shfl_up(ip, o, 64);
      if (lane >= o) { ic += vc; ip += vp; }
    }
    __shared__ int wtc[4], wtp[4];
    if (lane == 63) { wtc[wv] = ic; wtp[wv] = ip; }
    __syncthreads();
    int offc = 0, offp = 0;
    for (int w = 0; w < wv; w++) { offc += wtc[w]; offp += wtp[w]; }
    int irun = offc + ic - lc;
    int crun = offp + ip - lp;
    double acc = 0.0;
    #pragma unroll
    for (int j = 0; j < 4; j++) {
      const int n = (int)cnt[j];
      if (n) {
        const int bu = NB-1 - (t*4 + j);
        const double jac0 = (irun==0) ? 0.0 : 1.0 - (Pd - crun)/(Pd + irun - crun);
        irun += n; crun += (int)pos[j];
        const double jac1 = 1.0 - (Pd - crun)/(Pd + irun - crun);
        acc += ((bu + 0.5) * (2.0/NB)) * (jac1 - jac0);
      }
    }
    #pragma unroll
    for (int o=1;o<64;o<<=1) acc += __shfl_xor(acc, o, 64);
    __shared__ double racc[4];
    if (lane == 0) racc[wv] = acc;
    __syncthreads();
    if (t == 0) {
      const double tot = racc[0]+racc[1]+racc[2]+racc[3];
      atomicAdd(ws + OFF_LOSS, (float)(tot * (1.0/3.0)));
    }
  }
  if (t == 0) {
    __threadfence();
    unsigned int* wsu = (unsigned int*)ws;
    const unsigned int old = atomicAdd(&wsu[OFF_TICK], 1u);
    if (old == (unsigned)(B*K - 1)) {
      __threadfence();
      out[0] = *((volatile float*)(ws + OFF_LOSS));
    }
  }
}

extern "C" void kernel_launch(void* const* d_in, const int* in_sizes, int n_in,
                              void* d_out, int out_size, void* d_ws, size_t ws_size,
                              hipStream_t stream) {
  const float* pred = (const float*)d_in[0];
  const int*   inst = (const int*)d_in[1];
  float* ws  = (float*)d_ws;
  float* out = (float*)d_out;
  unsigned int* red  = ((unsigned int*)d_ws) + OFF_RED;
  unsigned int* part = ((unsigned int*)d_ws) + OFF_PART;
  (void)ws_size;
  void* args[6] = { (void*)&pred, (void*)&inst, (void*)&ws, (void*)&part,
                    (void*)&red, (void*)&out };
  hipError_t e = hipLaunchCooperativeKernel((const void*)k_mega, dim3(G, B), dim3(1024),
                                            args, 0, stream);
  if (e != hipSuccess) {
    // fallback: round-3 multi-kernel path
    hipMemsetAsync(d_ws, 0, 128, stream);
    k1_stats<<<dim3(NBLK1,B), 512, 0, stream>>>(pred, inst, ws);
    k3_fb   <<<dim3(G,B), 1024, 0, stream>>>(pred, inst, ws, part);
    k4a_reduce<<<dim3(B*K, 8), 128, 0, stream>>>(part, red);
    k4b_lovasz<<<B*K, 256, 0, stream>>>(red, ws, out);
  }
}

// Round 6
// 142.285 us; speedup vs baseline: 5.2819x; 5.2819x over previous
//
#include <hip/hip_runtime.h>

#define H 512
#define WID 1024
#define HW (H*WID)
#define B 4
#define K 8
#define NB 1024
#define G 128
#define NBLK1 128                          // k1 blocks per image

// ws word (4-byte) layout
#define OFF_LOSS  0
#define OFF_TICK  1                        // completion ticket (u32)
#define OFF_FIN   16                       // B*K*8 floats: only [+4]=cnt used
#define OFF_SPART 512                      // B*K*NBLK1*8 floats (stride 8)
#define OFF_RED   (OFF_SPART + B*K*NBLK1*8)   // B*K*NB u64 (cnt lo32 | pos hi32)

static __device__ __forceinline__ float frcp(float x){
#if __has_builtin(__builtin_amdgcn_rcpf)
  return __builtin_amdgcn_rcpf(x);
#else
  return 1.0f / x;
#endif
}
static __device__ __forceinline__ float fexp2(float x){
#if __has_builtin(__builtin_amdgcn_exp2f)
  return __builtin_amdgcn_exp2f(x);
#else
  return exp2f(x);
#endif
}
static __device__ __forceinline__ float ftanh(float x){
  return 1.0f - 2.0f * frcp(__expf(2.0f*x) + 1.0f);
}
static __device__ __forceinline__ float fsigmoid(float x){
  return frcp(1.0f + __expf(-x));
}

// ---------------- Kernel 1: per-(b,k) stats + zero red64/LOSS/TICK ----------------
__global__ __launch_bounds__(512) void k1_stats(const float* __restrict__ pred,
                                                const int* __restrict__ inst,
                                                float* __restrict__ ws,
                                                unsigned long long* __restrict__ red64) {
  const int b = blockIdx.y;
  __shared__ int4   ti[1024];
  __shared__ float4 ts[1024];
  __shared__ float  part5[K][5];
  // zero red64 (512 blocks x 64 u64 = 32768) + LOSS/TICK
  {
    const int blin = b*NBLK1 + blockIdx.x;
    if (threadIdx.x < 64) red64[(size_t)blin*64 + threadIdx.x] = 0ull;
    if (blin == 0 && threadIdx.x == 64) {
      ws[OFF_LOSS] = 0.0f;
      ((unsigned int*)ws)[OFF_TICK] = 0u;
    }
  }
  const float4* sig4 = (const float4*)(pred + (size_t)(8*b + 5) * HW);  // ch2 t=1
  const int4*   ins4 = (const int4*)(inst + (size_t)(2*b + 1) * HW);
  const int base4 = blockIdx.x * 1024;     // 1024 int4-groups per block
  #pragma unroll
  for (int i = 0; i < 2; i++) {
    const int q = threadIdx.x + i*512;
    ti[q] = ins4[base4 + q];
    ts[q] = sig4[base4 + q];
  }
  __syncthreads();
  const int wv = threadIdx.x >> 6, lane = threadIdx.x & 63;
  const int kk = wv + 1;
  float cnt=0.f, sx=0.f, sy=0.f, ss=0.f, ss2=0.f;
  #pragma unroll
  for (int j = 0; j < 16; j++) {
    const int q = lane + 64*j;
    const int4   iv = ti[q];
    const float4 sv = ts[q];
    const int p = (base4 + q) * 4;
    const float xm0 = (float)(p & (WID-1)) * (2.0f/2047.0f);
    const float ym  = (float)(p >> 10)     * (1.0f/1023.0f);
    const float m0 = (iv.x==kk)?1.f:0.f, m1=(iv.y==kk)?1.f:0.f,
                m2 = (iv.z==kk)?1.f:0.f, m3=(iv.w==kk)?1.f:0.f;
    const float msum = (m0+m1)+(m2+m3);
    cnt += msum;
    sx  += msum*xm0 + (m1 + 2.0f*m2 + 3.0f*m3)*(2.0f/2047.0f);
    sy  += msum*ym;
    ss  += m0*sv.x + m1*sv.y + m2*sv.z + m3*sv.w;
    ss2 += m0*sv.x*sv.x + m1*sv.y*sv.y + m2*sv.z*sv.z + m3*sv.w*sv.w;
  }
  #pragma unroll
  for (int o=1;o<64;o<<=1){
    cnt+=__shfl_xor(cnt,o,64);
    sx +=__shfl_xor(sx, o,64);
    sy +=__shfl_xor(sy, o,64);
    ss +=__shfl_xor(ss, o,64);
    ss2+=__shfl_xor(ss2,o,64);
  }
  if (lane == 0) {
    part5[wv][0]=cnt; part5[wv][1]=sx; part5[wv][2]=sy; part5[wv][3]=ss; part5[wv][4]=ss2;
  }
  __syncthreads();
  if (threadIdx.x < K*8) {
    const int w = threadIdx.x >> 3, c = threadIdx.x & 7;
    if (c < 5)
      ws[OFF_SPART + ((size_t)(b*K + w)*NBLK1 + blockIdx.x)*8 + c] = part5[w][c];
  }
}

// ---------------- Kernel 3: main pass (k2 fused) — hist flushed via global u64 atomics ----------------
// 1024 thr (16 waves), G=128 -> 2 blocks/CU = 32 waves/CU (round-3 proven body:
// 56 VGPR, no spill). Epilogue: zero-skip u64 atomicAdd into red64 (L2-resident,
// 256 KB) — replaces the 16.8 MB part-slab write + k4a's 16.8 MB re-read + one
// dispatch boundary.
__global__ __launch_bounds__(1024, 8) void k3_main(const float* __restrict__ pred,
                                                   const int* __restrict__ inst,
                                                   float* __restrict__ ws,
                                                   unsigned long long* __restrict__ red64) {
  const int b = blockIdx.y, g = blockIdx.x;
  __shared__ unsigned int hist[K*NB];           // pos<<16 | cnt, 32 KiB
  __shared__ float4 finL[K];
  __shared__ float  vlocL[K];
  for (int i = threadIdx.x*4; i < K*NB; i += 1024*4)
    *(uint4*)&hist[i] = make_uint4(0u,0u,0u,0u);
  const int wv = threadIdx.x >> 6, lane = threadIdx.x & 63;
  // ---- fused k2: wave wv (0..7) reduces spart for k=wv ----
  if (wv < K) {
    const float* p = ws + OFF_SPART + (size_t)(b*K + wv)*NBLK1*8;
    const float4 q0 = *(const float4*)(p + (size_t)lane*8);
    const float  e0 = p[(size_t)lane*8 + 4];
    const float4 q1 = *(const float4*)(p + (size_t)(lane+64)*8);
    const float  e1 = p[(size_t)(lane+64)*8 + 4];
    float a0=q0.x+q1.x, a1=q0.y+q1.y, a2=q0.z+q1.z, a3=q0.w+q1.w, a4=e0+e1;
    #pragma unroll
    for (int o=1;o<64;o<<=1){
      a0+=__shfl_xor(a0,o,64); a1+=__shfl_xor(a1,o,64); a2+=__shfl_xor(a2,o,64);
      a3+=__shfl_xor(a3,o,64); a4+=__shfl_xor(a4,o,64);
    }
    if (lane == 0) {
      const float cnt=a0, sx=a1, sy=a2, ss=a3, ss2=a4;
      const float present = (cnt > 0.0f) ? 1.0f : 0.0f;
      const float safe = fmaxf(cnt, 1.0f);
      const float cx = sx/safe, cy = sy/safe, sm = ss/safe;
      const float var = (ss2 - 2.0f*sm*ss + sm*sm*cnt)/safe;   // N_SIGMA=1
      const float sexp = expf(10.0f * sm);
      const float L2E = 1.4426950408889634f;
      finL[wv] = make_float4(-sexp*L2E,                        // a
                              2.0f*sexp*cx*L2E,                // bx
                              2.0f*sexp*cy*L2E,                // by
                             -sexp*(cx*cx + cy*cy)*L2E + 10.0f); // d0 (+10 = x1024 scale)
      vlocL[wv] = present * 10.0f * var * (1.0f/3.0f);         // W_VAR=10, /(B-1)
      if (g == 0) ws[OFF_FIN + (b*K + wv)*8 + 4] = cnt;        // for k4b
    }
  }
  __syncthreads();
  float4 fr[K];
  #pragma unroll
  for (int k=0;k<K;k++) fr[k] = finL[k];      // broadcast reads
  const float4* p0 = (const float4*)(pred + (size_t)(8*b+1)*HW);
  const float4* p1 = (const float4*)(pred + (size_t)(8*b+3)*HW);
  const float4* p3 = (const float4*)(pred + (size_t)(8*b+7)*HW);
  const int4*   in4 = (const int4*)(inst + (size_t)(2*b+1)*HW);
  float sAcc = 0.0f;
  const int idx = g*1024 + threadIdx.x;       // one quad per thread
  {
    const int4   iv = in4[idx];
    const float4 f0 = p0[idx];
    const float4 f1 = p1[idx];
    const float4 f3 = p3[idx];
    const int p = idx * 4;
    const float xm0 = (float)(p & (WID-1)) * (2.0f/2047.0f);
    const float ym  = (float)(p >> 10)     * (1.0f/1023.0f);
    const int ivv[4] = {iv.x, iv.y, iv.z, iv.w};
    float pxv[4], pyv[4], t2v[4], down[4];
    {
      const float a0v[4] = {f0.x, f0.y, f0.z, f0.w};
      const float a1v[4] = {f1.x, f1.y, f1.z, f1.w};
      #pragma unroll
      for (int e=0;e<4;e++){
        pxv[e] = ftanh(a0v[e]) + xm0 + (float)e*(2.0f/2047.0f);
        pyv[e] = ftanh(a1v[e]) + ym;
        t2v[e] = pxv[e]*pxv[e] + pyv[e]*pyv[e];
        down[e] = 0.0f;
      }
    }
    #pragma unroll
    for (int j=0;j<K;j++){
      const float4 f = fr[j];
      int buv[4]; unsigned addv[4];
      #pragma unroll
      for (int e=0;e<4;e++){
        const float u = fmaf(f.x, t2v[e], fmaf(f.y, pxv[e], fmaf(f.z, pyv[e], f.w)));
        const float v = fexp2(u);                 // 1024*dist in [0,1024]
        int vi = (int)v; vi = (vi > NB-1) ? NB-1 : vi;
        const bool own = (ivv[e] == j+1);
        if (own) down[e] = v;
        buv[e] = own ? (NB-1 - vi) : vi;
        addv[e] = own ? 0x10001u : 1u;
      }
      // merge runs of equal buckets within the quad
      int cur = buv[0]; unsigned acc = addv[0];
      #pragma unroll
      for (int e=1;e<4;e++){
        const bool same = (buv[e] == cur);
        if (!same) atomicAdd(&hist[j*NB + cur], acc);
        acc = same ? acc + addv[e] : addv[e];
        cur = buv[e];
      }
      atomicAdd(&hist[j*NB + cur], acc);
    }
    {
      const float sdv[4] = {fsigmoid(f3.x), fsigmoid(f3.y), fsigmoid(f3.z), fsigmoid(f3.w)};
      #pragma unroll
      for (int e=0;e<4;e++){
        const float d  = (ivv[e] == 0) ? 0.0f : down[e] * (1.0f/1024.0f);
        const float df = sdv[e] - d;
        sAcc += df*df;                            // bg: sd^2; fg: (sd-dist)^2
      }
    }
  }
  __syncthreads();
  // flush hist -> global red64 (zero-skip u64 atomics; i = k*NB + bu)
  {
    const size_t rb = (size_t)b * (K*NB);
    #pragma unroll
    for (int r = 0; r < 8; r++) {
      const int i = threadIdx.x + r*1024;
      const unsigned v = hist[i];
      if (v)
        atomicAdd(&red64[rb + i],
                  (unsigned long long)(v & 0xFFFFu) |
                  ((unsigned long long)(v >> 16) << 32));
    }
  }
  #pragma unroll
  for (int o=1;o<64;o<<=1) sAcc += __shfl_xor(sAcc, o, 64);
  __shared__ float wsum[16];
  if (lane == 0) wsum[wv] = sAcc;
  __syncthreads();
  if (threadIdx.x == 0) {
    float tot = 0.f;
    #pragma unroll
    for (int w = 0; w < 16; w++) tot += wsum[w];
    float add = tot * (1.0f/((float)HW * 3.0f));  // W_SEED /npix /(B-1)
    if (g == 0) {
      #pragma unroll
      for (int k = 0; k < K; k++) add += vlocL[k];  // var loss, once per image
    }
    atomicAdd(ws + OFF_LOSS, add);
  }
}

// ---------------- Kernel 4b: Lovász from red64 + final output ----------------
__global__ __launch_bounds__(256) void k4b_lovasz(const unsigned long long* __restrict__ red64,
                                                   float* __restrict__ ws,
                                                   float* __restrict__ out) {
  const int bk = blockIdx.x;                    // b*K + k
  const float cntF = ws[OFF_FIN + bk*8 + 4];
  const int t = threadIdx.x;
  if (cntF > 0.0f) {
    const double Pd = (double)cntF;
    const int lane = t & 63, wv = t >> 6;
    unsigned int cnt[4], pos[4];
    #pragma unroll
    for (int j = 0; j < 4; j++) {
      const int bu = NB-1 - (t*4 + j);            // descending error order
      const unsigned long long vv = red64[(size_t)bk*NB + bu];
      cnt[j] = (unsigned int)(vv & 0xFFFFFFFFull);
      pos[j] = (unsigned int)(vv >> 32);
    }
    const int lc = (int)(cnt[0]+cnt[1]+cnt[2]+cnt[3]);
    const int lp = (int)(pos[0]+pos[1]+pos[2]+pos[3]);
    int ic = lc, ip = lp;
    #pragma unroll
    for (int o=1;o<64;o<<=1){
      const int vc = __shfl_up(ic, o, 64);
      const int vp = __shfl_up(ip, o, 64);
      if (lane >= o) { ic += vc; ip += vp; }
    }
    __shared__ int wtc[4], wtp[4];
    if (lane == 63) { wtc[wv] = ic; wtp[wv] = ip; }
    __syncthreads();
    int offc = 0, offp = 0;
    for (int w = 0; w < wv; w++) { offc += wtc[w]; offp += wtp[w]; }
    int irun = offc + ic - lc;                    // exclusive prefixes
    int crun = offp + ip - lp;
    double acc = 0.0;
    #pragma unroll
    for (int j = 0; j < 4; j++) {
      const int n = (int)cnt[j];
      if (n) {
        const int bu = NB-1 - (t*4 + j);
        const double jac0 = (irun==0) ? 0.0 : 1.0 - (Pd - crun)/(Pd + irun - crun);
        irun += n; crun += (int)pos[j];
        const double jac1 = 1.0 - (Pd - crun)/(Pd + irun - crun);
        acc += ((bu + 0.5) * (2.0/NB)) * (jac1 - jac0);
      }
    }
    #pragma unroll
    for (int o=1;o<64;o<<=1) acc += __shfl_xor(acc, o, 64);
    __shared__ double racc[4];
    if (lane == 0) racc[wv] = acc;
    __syncthreads();
    if (t == 0) {
      const double tot = racc[0]+racc[1]+racc[2]+racc[3];
      atomicAdd(ws + OFF_LOSS, (float)(tot * (1.0/3.0)));   // W_INST=1, /(B-1)
    }
  }
  // completion ticket: last block writes the output
  if (t == 0) {
    __threadfence();
    unsigned int* wsu = (unsigned int*)ws;
    const unsigned int old = atomicAdd(&wsu[OFF_TICK], 1u);
    if (old == (unsigned)(B*K - 1)) {
      __threadfence();
      out[0] = *((volatile float*)(ws + OFF_LOSS));
    }
  }
}

extern "C" void kernel_launch(void* const* d_in, const int* in_sizes, int n_in,
                              void* d_out, int out_size, void* d_ws, size_t ws_size,
                              hipStream_t stream) {
  const float* pred = (const float*)d_in[0];
  const int*   inst = (const int*)d_in[1];
  float* ws  = (float*)d_ws;
  float* out = (float*)d_out;
  unsigned long long* red64 =
      (unsigned long long*)(((unsigned int*)d_ws) + OFF_RED);
  (void)ws_size;
  k1_stats  <<<dim3(NBLK1,B), 512, 0, stream>>>(pred, inst, ws, red64);
  k3_main   <<<dim3(G,B), 1024, 0, stream>>>(pred, inst, ws, red64);
  k4b_lovasz<<<B*K, 256, 0, stream>>>(red64, ws, out);
}

// Round 7
// 133.353 us; speedup vs baseline: 5.6356x; 1.0670x over previous
//
#include <hip/hip_runtime.h>

#define H 512
#define WID 1024
#define HW (H*WID)
#define B 4
#define K 8
#define NB 1024
#define NBLK1 128                          // k1 blocks per image

// ws word (4-byte) layout
#define OFF_LOSS  0
#define OFF_TICK  1                        // completion ticket (u32)
#define OFF_FIN   16                       // B*K*8 floats: only [+4]=cnt used
#define OFF_SPART 512                      // B*K*NBLK1*8 floats (stride 8)
#define OFF_PART  (OFF_SPART + B*K*NBLK1*8)   // B*G*K*NB packed u32 (pos<<16|cnt)

static __device__ __forceinline__ float frcp(float x){
#if __has_builtin(__builtin_amdgcn_rcpf)
  return __builtin_amdgcn_rcpf(x);
#else
  return 1.0f / x;
#endif
}
static __device__ __forceinline__ float fexp2(float x){
#if __has_builtin(__builtin_amdgcn_exp2f)
  return __builtin_amdgcn_exp2f(x);
#else
  return exp2f(x);
#endif
}
static __device__ __forceinline__ float ftanh(float x){
  return 1.0f - 2.0f * frcp(__expf(2.0f*x) + 1.0f);
}
static __device__ __forceinline__ float fsigmoid(float x){
  return frcp(1.0f + __expf(-x));
}

// ---------------- Kernel 1: per-(b,k) stats + zero LOSS/TICK ----------------
__global__ __launch_bounds__(512) void k1_stats(const float* __restrict__ pred,
                                                const int* __restrict__ inst,
                                                float* __restrict__ ws) {
  const int b = blockIdx.y;
  __shared__ int4   ti[1024];
  __shared__ float4 ts[1024];
  __shared__ float  part5[K][5];
  if (b == 0 && blockIdx.x == 0) {
    if (threadIdx.x == 0) ws[OFF_LOSS] = 0.0f;
    if (threadIdx.x == 1) ((unsigned int*)ws)[OFF_TICK] = 0u;
  }
  const float4* sig4 = (const float4*)(pred + (size_t)(8*b + 5) * HW);  // ch2 t=1
  const int4*   ins4 = (const int4*)(inst + (size_t)(2*b + 1) * HW);
  const int base4 = blockIdx.x * 1024;     // 1024 int4-groups per block
  #pragma unroll
  for (int i = 0; i < 2; i++) {
    const int q = threadIdx.x + i*512;
    ti[q] = ins4[base4 + q];
    ts[q] = sig4[base4 + q];
  }
  __syncthreads();
  const int wv = threadIdx.x >> 6, lane = threadIdx.x & 63;
  const int kk = wv + 1;
  float cnt=0.f, sx=0.f, sy=0.f, ss=0.f, ss2=0.f;
  #pragma unroll
  for (int j = 0; j < 16; j++) {
    const int q = lane + 64*j;
    const int4   iv = ti[q];
    const float4 sv = ts[q];
    const int p = (base4 + q) * 4;
    const float xm0 = (float)(p & (WID-1)) * (2.0f/2047.0f);
    const float ym  = (float)(p >> 10)     * (1.0f/1023.0f);
    const float m0 = (iv.x==kk)?1.f:0.f, m1=(iv.y==kk)?1.f:0.f,
                m2 = (iv.z==kk)?1.f:0.f, m3=(iv.w==kk)?1.f:0.f;
    const float msum = (m0+m1)+(m2+m3);
    cnt += msum;
    sx  += msum*xm0 + (m1 + 2.0f*m2 + 3.0f*m3)*(2.0f/2047.0f);
    sy  += msum*ym;
    ss  += m0*sv.x + m1*sv.y + m2*sv.z + m3*sv.w;
    ss2 += m0*sv.x*sv.x + m1*sv.y*sv.y + m2*sv.z*sv.z + m3*sv.w*sv.w;
  }
  #pragma unroll
  for (int o=1;o<64;o<<=1){
    cnt+=__shfl_xor(cnt,o,64);
    sx +=__shfl_xor(sx, o,64);
    sy +=__shfl_xor(sy, o,64);
    ss +=__shfl_xor(ss, o,64);
    ss2+=__shfl_xor(ss2,o,64);
  }
  if (lane == 0) {
    part5[wv][0]=cnt; part5[wv][1]=sx; part5[wv][2]=sy; part5[wv][3]=ss; part5[wv][4]=ss2;
  }
  __syncthreads();
  if (threadIdx.x < K*8) {
    const int w = threadIdx.x >> 3, c = threadIdx.x & 7;
    if (c < 5)
      ws[OFF_SPART + ((size_t)(b*K + w)*NBLK1 + blockIdx.x)*8 + c] = part5[w][c];
  }
}

// ---------------- Kernel 3: main pass (k2 fused) — round-3 proven body ----------------
// 1024 thr (16 waves), G=128 -> 2 blocks/CU = 32 waves/CU. LDS hist flushed as
// plain coalesced uint4 stores to the part slab (device atomics proved ~15 µs
// slower in round 6 — do NOT reintroduce).
template<int G>
__global__ __launch_bounds__(1024, 8) void k3_main(const float* __restrict__ pred,
                                                   const int* __restrict__ inst,
                                                   float* __restrict__ ws,
                                                   unsigned int* __restrict__ part) {
  const int b = blockIdx.y, g = blockIdx.x;
  __shared__ unsigned int hist[K*NB];           // pos<<16 | cnt, 32 KiB
  __shared__ float4 finL[K];
  __shared__ float  vlocL[K];
  for (int i = threadIdx.x*4; i < K*NB; i += 1024*4)
    *(uint4*)&hist[i] = make_uint4(0u,0u,0u,0u);
  const int wv = threadIdx.x >> 6, lane = threadIdx.x & 63;
  // ---- fused k2: wave wv (0..7) reduces spart for k=wv ----
  if (wv < K) {
    const float* p = ws + OFF_SPART + (size_t)(b*K + wv)*NBLK1*8;
    const float4 q0 = *(const float4*)(p + (size_t)lane*8);
    const float  e0 = p[(size_t)lane*8 + 4];
    const float4 q1 = *(const float4*)(p + (size_t)(lane+64)*8);
    const float  e1 = p[(size_t)(lane+64)*8 + 4];
    float a0=q0.x+q1.x, a1=q0.y+q1.y, a2=q0.z+q1.z, a3=q0.w+q1.w, a4=e0+e1;
    #pragma unroll
    for (int o=1;o<64;o<<=1){
      a0+=__shfl_xor(a0,o,64); a1+=__shfl_xor(a1,o,64); a2+=__shfl_xor(a2,o,64);
      a3+=__shfl_xor(a3,o,64); a4+=__shfl_xor(a4,o,64);
    }
    if (lane == 0) {
      const float cnt=a0, sx=a1, sy=a2, ss=a3, ss2=a4;
      const float present = (cnt > 0.0f) ? 1.0f : 0.0f;
      const float safe = fmaxf(cnt, 1.0f);
      const float cx = sx/safe, cy = sy/safe, sm = ss/safe;
      const float var = (ss2 - 2.0f*sm*ss + sm*sm*cnt)/safe;   // N_SIGMA=1
      const float sexp = expf(10.0f * sm);
      const float L2E = 1.4426950408889634f;
      finL[wv] = make_float4(-sexp*L2E,                        // a
                              2.0f*sexp*cx*L2E,                // bx
                              2.0f*sexp*cy*L2E,                // by
                             -sexp*(cx*cx + cy*cy)*L2E + 10.0f); // d0 (+10 = x1024 scale)
      vlocL[wv] = present * 10.0f * var * (1.0f/3.0f);         // W_VAR=10, /(B-1)
      if (g == 0) ws[OFF_FIN + (b*K + wv)*8 + 4] = cnt;        // for k4ab
    }
  }
  __syncthreads();
  float4 fr[K];
  #pragma unroll
  for (int k=0;k<K;k++) fr[k] = finL[k];      // broadcast reads
  const float4* p0 = (const float4*)(pred + (size_t)(8*b+1)*HW);
  const float4* p1 = (const float4*)(pred + (size_t)(8*b+3)*HW);
  const float4* p3 = (const float4*)(pred + (size_t)(8*b+7)*HW);
  const int4*   in4 = (const int4*)(inst + (size_t)(2*b+1)*HW);
  float sAcc = 0.0f;
  constexpr int CH4 = HW / (G*4);
  const int base4 = g * CH4;
  for (int q0 = 0; q0 < CH4; q0 += 1024) {
    const int idx = base4 + q0 + threadIdx.x;
    const int4   iv = in4[idx];
    const float4 f0 = p0[idx];
    const float4 f1 = p1[idx];
    const float4 f3 = p3[idx];
    const int p = idx * 4;
    const float xm0 = (float)(p & (WID-1)) * (2.0f/2047.0f);
    const float ym  = (float)(p >> 10)     * (1.0f/1023.0f);
    const int ivv[4] = {iv.x, iv.y, iv.z, iv.w};
    float pxv[4], pyv[4], t2v[4], down[4];
    {
      const float a0v[4] = {f0.x, f0.y, f0.z, f0.w};
      const float a1v[4] = {f1.x, f1.y, f1.z, f1.w};
      #pragma unroll
      for (int e=0;e<4;e++){
        pxv[e] = ftanh(a0v[e]) + xm0 + (float)e*(2.0f/2047.0f);
        pyv[e] = ftanh(a1v[e]) + ym;
        t2v[e] = pxv[e]*pxv[e] + pyv[e]*pyv[e];
        down[e] = 0.0f;
      }
    }
    #pragma unroll
    for (int j=0;j<K;j++){
      const float4 f = fr[j];
      int buv[4]; unsigned addv[4];
      #pragma unroll
      for (int e=0;e<4;e++){
        const float u = fmaf(f.x, t2v[e], fmaf(f.y, pxv[e], fmaf(f.z, pyv[e], f.w)));
        const float v = fexp2(u);                 // 1024*dist in [0,1024]
        int vi = (int)v; vi = (vi > NB-1) ? NB-1 : vi;
        const bool own = (ivv[e] == j+1);
        if (own) down[e] = v;
        buv[e] = own ? (NB-1 - vi) : vi;
        addv[e] = own ? 0x10001u : 1u;
      }
      // merge runs of equal buckets within the quad
      int cur = buv[0]; unsigned acc = addv[0];
      #pragma unroll
      for (int e=1;e<4;e++){
        const bool same = (buv[e] == cur);
        if (!same) atomicAdd(&hist[j*NB + cur], acc);
        acc = same ? acc + addv[e] : addv[e];
        cur = buv[e];
      }
      atomicAdd(&hist[j*NB + cur], acc);
    }
    {
      const float sdv[4] = {fsigmoid(f3.x), fsigmoid(f3.y), fsigmoid(f3.z), fsigmoid(f3.w)};
      #pragma unroll
      for (int e=0;e<4;e++){
        const float d  = (ivv[e] == 0) ? 0.0f : down[e] * (1.0f/1024.0f);
        const float df = sdv[e] - d;
        sAcc += df*df;                            // bg: sd^2; fg: (sd-dist)^2
      }
    }
  }
  __syncthreads();
  unsigned int* dst = part + ((size_t)b*G + g)*(K*NB);
  for (int i = threadIdx.x*4; i < K*NB; i += 1024*4)
    *(uint4*)&dst[i] = *(const uint4*)&hist[i];
  #pragma unroll
  for (int o=1;o<64;o<<=1) sAcc += __shfl_xor(sAcc, o, 64);
  __shared__ float wsum[16];
  if (lane == 0) wsum[wv] = sAcc;
  __syncthreads();
  if (threadIdx.x == 0) {
    float tot = 0.f;
    #pragma unroll
    for (int w = 0; w < 16; w++) tot += wsum[w];
    float add = tot * (1.0f/((float)HW * 3.0f));  // W_SEED /npix /(B-1)
    if (g == 0) {
      #pragma unroll
      for (int k = 0; k < K; k++) add += vlocL[k];  // var loss, once per image
    }
    atomicAdd(ws + OFF_LOSS, add);
  }
}

// ---------------- Kernel 4: fused G-reduction + Lovász + output ----------------
// 32 blocks x 1024 thr: thread t owns bucket bu = NB-1-t (descending error
// order). Per-g the block reads a contiguous (reversed) 4 KB line -> coalesced;
// 512 KB/block, L2-resident. Then 1-bucket/thread block scan + Lovász.
__global__ __launch_bounds__(1024) void k4ab_lovasz(const unsigned int* __restrict__ part,
                                                    float* __restrict__ ws,
                                                    float* __restrict__ out, int G_) {
  const int bk = blockIdx.x;                    // b*K + k
  const int b = bk >> 3, k = bk & 7;
  const int t = threadIdx.x, lane = t & 63, wv = t >> 6;
  __shared__ int    wtc[16], wtp[16];
  __shared__ double racc[16];
  const float cntF = ws[OFF_FIN + bk*8 + 4];
  if (cntF > 0.0f) {
    const double Pd = (double)cntF;
    const int bu = NB-1 - t;                    // descending error order
    unsigned rc = 0, rp = 0;
    const unsigned int* base = part + (size_t)b*G_*(K*NB) + (size_t)k*NB + bu;
    #pragma unroll 8
    for (int g = 0; g < G_; g++) {
      const unsigned v = base[(size_t)g*(K*NB)];
      rc += v & 0xFFFFu;
      rp += v >> 16;
    }
    int ic = (int)rc, ip = (int)rp;
    #pragma unroll
    for (int o=1;o<64;o<<=1){
      const int vc = __shfl_up(ic, o, 64);
      const int vp = __shfl_up(ip, o, 64);
      if (lane >= o) { ic += vc; ip += vp; }
    }
    if (lane == 63) { wtc[wv] = ic; wtp[wv] = ip; }
    __syncthreads();
    int offc = 0, offp = 0;
    for (int w = 0; w < wv; w++) { offc += wtc[w]; offp += wtp[w]; }
    const int irun = offc + ic - (int)rc;       // exclusive prefixes
    const int crun = offp + ip - (int)rp;
    double acc = 0.0;
    if (rc) {
      const double jac0 = (irun==0) ? 0.0 : 1.0 - (Pd - crun)/(Pd + irun - crun);
      const int ir1 = irun + (int)rc, cr1 = crun + (int)rp;
      const double jac1 = 1.0 - (Pd - cr1)/(Pd + ir1 - cr1);
      acc = ((bu + 0.5) * (2.0/NB)) * (jac1 - jac0);
    }
    #pragma unroll
    for (int o=1;o<64;o<<=1) acc += __shfl_xor(acc, o, 64);
    if (lane == 0) racc[wv] = acc;
    __syncthreads();
    if (t == 0) {
      double tot = 0.0;
      #pragma unroll
      for (int w = 0; w < 16; w++) tot += racc[w];
      atomicAdd(ws + OFF_LOSS, (float)(tot * (1.0/3.0)));   // W_INST=1, /(B-1)
    }
  }
  // completion ticket: last block writes the output
  if (t == 0) {
    __threadfence();
    unsigned int* wsu = (unsigned int*)ws;
    const unsigned int old = atomicAdd(&wsu[OFF_TICK], 1u);
    if (old == (unsigned)(B*K - 1)) {
      __threadfence();
      out[0] = *((volatile float*)(ws + OFF_LOSS));
    }
  }
}

extern "C" void kernel_launch(void* const* d_in, const int* in_sizes, int n_in,
                              void* d_out, int out_size, void* d_ws, size_t ws_size,
                              hipStream_t stream) {
  const float* pred = (const float*)d_in[0];
  const int*   inst = (const int*)d_in[1];
  float* ws  = (float*)d_ws;
  float* out = (float*)d_out;
  unsigned int* part = ((unsigned int*)d_ws) + OFF_PART;
  int G = 128;
  while (G > 32 && ws_size < ((size_t)OFF_PART + (size_t)B*G*K*NB)*4) G >>= 1;
  k1_stats<<<dim3(NBLK1,B), 512, 0, stream>>>(pred, inst, ws);
  if      (G == 128) k3_main<128><<<dim3(128,B), 1024, 0, stream>>>(pred, inst, ws, part);
  else if (G ==  64) k3_main< 64><<<dim3( 64,B), 1024, 0, stream>>>(pred, inst, ws, part);
  else               k3_main< 32><<<dim3( 32,B), 1024, 0, stream>>>(pred, inst, ws, part);
  k4ab_lovasz<<<B*K, 1024, 0, stream>>>(part, ws, out, G);
}